// Round 6
// baseline (5636.352 us; speedup 1.0000x reference)
//
#include <hip/hip_runtime.h>

#define NL 10   // layers
#define NB 64   // batch
#define NT 2048 // time steps
#define NI 14   // input features
#define NH 100  // hidden
#define NS 4    // batch slices
#define BPS 16  // batch rows per slice (= MFMA M)
#define CH 4    // timesteps per published chunk
#define NTC (NT / CH)
#define HSTR 136  // LDS h row stride in ushorts (272B; (rowl+kg)%8 uniform)
#define RC 128    // ring row cols (bf16, zero-padded 100..127)
#define PLANE (CH * BPS * RC)  // ushorts per (hi|lo) plane = 8192
#define RSLOT2 (2 * PLANE)     // ushorts per chunk slot (32 KB)
#define NTHR 256
#define FLAGW 16
#define FLAGBYTES 8192
#define ABORT_IDX (NL * NS * FLAGW)
#define SPIN_CAP (1 << 18)

typedef __attribute__((ext_vector_type(8))) short short8v;  // 8 bf16 = 4 VGPR
typedef __attribute__((ext_vector_type(4))) float f32x4;

__device__ __forceinline__ unsigned ld_rlx(const unsigned* p) {
  return __hip_atomic_load(p, __ATOMIC_RELAXED, __HIP_MEMORY_SCOPE_AGENT);
}
__device__ __forceinline__ void st_rlx(unsigned* p, unsigned v) {
  __hip_atomic_store(p, v, __ATOMIC_RELAXED, __HIP_MEMORY_SCOPE_AGENT);
}
__device__ __forceinline__ unsigned short f2bf(float f) {
  unsigned u = __float_as_uint(f);
  return (unsigned short)((u + 0x7FFFu + ((u >> 16) & 1u)) >> 16);  // RNE
}
__device__ __forceinline__ float bf2f(unsigned short u) {
  return __uint_as_float((unsigned)u << 16);
}
__device__ __forceinline__ float fast_tanh(float v) {
  float e = __expf(2.f * v);
  return 1.f - 2.f / (e + 1.f);
}

// Device-coherent 16B ring accesses: sc0 sc1 bypass the incoherent L1/L2,
// moving data via the die-level coherence point (L3). No L2 wb/inv fences.
__device__ __forceinline__ short8v ld16_sys(const unsigned short* p) {
  short8v r;
  asm volatile("global_load_dwordx4 %0, %1, off sc0 sc1"
               : "=v"(r) : "v"(p) : "memory");
  return r;
}
__device__ __forceinline__ void st16_sys(unsigned short* p, short8v v) {
  asm volatile("global_store_dwordx4 %0, %1, off sc0 sc1"
               :: "v"(p), "v"(v) : "memory");
}

// Relaxed-poll with watchdog: returns 1 on abort (timeout here or elsewhere).
__device__ __forceinline__ int wait_ge(const unsigned* p, unsigned tgt,
                                       unsigned* abortf) {
  int iters = 0;
  while (ld_rlx(p) < tgt) {
    if (++iters > SPIN_CAP) { st_rlx(abortf, 1u); return 1; }
    if ((iters & 63) == 0 && ld_rlx(abortf) != 0) return 1;
    __builtin_amdgcn_s_sleep(2);
  }
  return 0;
}

__global__ void zero_flags(unsigned* p) {
  p[blockIdx.x * 256 + threadIdx.x] = 0u;
}

__global__ __launch_bounds__(NTHR, 1)
void rnn_mfma(const float* __restrict__ x, const float* __restrict__ hidden,
              const float* __restrict__ w_ih0, const float* __restrict__ w_ihL,
              const float* __restrict__ w_hh, const float* __restrict__ b_ih,
              const float* __restrict__ b_hh, const float* __restrict__ fc_w,
              const float* __restrict__ fc_b, float* __restrict__ out,
              float* __restrict__ hfin, unsigned* __restrict__ prog,
              unsigned short* __restrict__ ring, int D) {
  __shared__ unsigned short hHi[BPS][HSTR];  // h hi-plane, cols >=100 zero
  __shared__ unsigned short hLo[BPS][HSTR];  // h lo-plane (residual)
  __shared__ float fcwL[112];
  __shared__ int sAbort;

  const int bid = blockIdx.x;
  const int l = bid / NS;
  const int s = bid - l * NS;
  const int tid = threadIdx.x;
  const int b0 = s * BPS;
  const int w = tid >> 6;        // wave id 0..3
  const int ln = tid & 63;       // lane in wave
  const int rowl = ln & 15;      // A row / B col / D col index
  const int kg = (ln >> 4) & 3;  // k-group (8 k's per K=32 chunk)

  // ---- init LDS: h0 split hi/lo, fc weights ----
  for (int i = tid; i < BPS * HSTR; i += NTHR) {
    int r = i / HSTR, cc = i - r * HSTR;
    unsigned short hv = 0, lv = 0;
    if (cc < NH) {
      float f = hidden[(size_t)l * NB * NH + (size_t)(b0 + r) * NH + cc];
      hv = f2bf(f);
      lv = f2bf(f - bf2f(hv));
    }
    (&hHi[0][0])[i] = hv;
    (&hLo[0][0])[i] = lv;
  }
  for (int i = tid; i < 112; i += NTHR) fcwL[i] = (i < NH) ? fc_w[i] : 0.f;
  if (tid == 0) sAbort = 0;

  // ---- persistent weight B-fragments in VGPRs (wave w: cols 2w*16, (2w+1)*16) ----
  const int j0 = (w * 2) * 16 + rowl;
  const int j1 = (w * 2 + 1) * 16 + rowl;
  const float* Whh = w_hh + (size_t)l * NH * NH;
  const float* Wih = (l == 0) ? w_ih0 : (w_ihL + (size_t)(l - 1) * NH * NH);
  const int KI = (l == 0) ? NI : NH;

  short8v bhh0[4], bhh1[4], bih0[4], bih1[4];
#pragma unroll
  for (int kc = 0; kc < 4; ++kc) {
    short8v f0 = {}, f1 = {}, g0 = {}, g1 = {};
    const int kb = kc * 32 + kg * 8;
#pragma unroll
    for (int e = 0; e < 8; ++e) {
      const int k = kb + e;
      if (k < NH) {
        if (j0 < NH) f0[e] = (short)f2bf(Whh[j0 * NH + k]);
        if (j1 < NH) f1[e] = (short)f2bf(Whh[j1 * NH + k]);
      }
      if (k < KI) {
        if (j0 < NH) g0[e] = (short)f2bf(Wih[j0 * KI + k]);
        if (j1 < NH) g1[e] = (short)f2bf(Wih[j1 * KI + k]);
      }
    }
    bhh0[kc] = f0; bhh1[kc] = f1; bih0[kc] = g0; bih1[kc] = g1;
  }
  const float bias0 = (j0 < NH) ? b_ih[l * NH + j0] + b_hh[l * NH + j0] : 0.f;
  const float bias1 = (j1 < NH) ? b_ih[l * NH + j1] + b_hh[l * NH + j1] : 0.f;
  const float fcb = fc_b[0];

  const unsigned* pin = prog + ((l > 0 ? (l - 1) * NS + s : 0)) * FLAGW;
  const unsigned* pout = prog + ((l < NL - 1 ? (l + 1) * NS + s : 0)) * FLAGW;
  unsigned* pme = prog + (l * NS + s) * FLAGW;
  unsigned* abortf = prog + ABORT_IDX;

  const unsigned short* rin =
      ring + (size_t)(l > 0 ? (l - 1) * NS + s : 0) * D * RSLOT2;
  unsigned short* rout = ring + (size_t)(l * NS + s) * D * RSLOT2;

  __syncthreads();

  for (int c = 0; c < NTC; ++c) {
    // ---- chunk-level sync (relaxed polls; data coherence via sc0sc1) ----
    if (tid == 0) {
      int ab = 0;
      if (l > 0) ab |= wait_ge(pin, (unsigned)(c + 1), abortf);
      if (!ab && l < NL - 1 && c >= D)
        ab |= wait_ge(pout, (unsigned)(c - D + 1), abortf);
      sAbort = ab;
    }
    __syncthreads();
    if (sAbort) return;

    // ---- layer-0: stage x hi/lo fragments for the chunk (cached loads) ----
    short8v xh[CH], xl[CH];
    if (l == 0) {
#pragma unroll
      for (int st = 0; st < CH; ++st) {
        short8v hh = {}, ll = {};
        const float* xp =
            x + (size_t)(b0 + rowl) * (NT * NI) + (size_t)(c * CH + st) * NI;
        if (kg < 2) {
#pragma unroll
          for (int e = 0; e < 8; ++e) {
            const int k = kg * 8 + e;
            if (k < NI) {
              float f = xp[k];
              unsigned short hu = f2bf(f);
              hh[e] = (short)hu;
              ll[e] = (short)f2bf(f - bf2f(hu));
            }
          }
        }
        xh[st] = hh; xl[st] = ll;
      }
    }

    const unsigned short* rbc = rin + (size_t)(c % D) * RSLOT2;
    unsigned short* robc = rout + (size_t)(c % D) * RSLOT2;

    // ---- CH recurrent steps ----
#pragma unroll
    for (int st = 0; st < CH; ++st) {
      const int t = c * CH + st;

      // ih fragments: coherent ring loads issued FIRST; their ~L3 latency
      // hides under the hh MFMA chain below.
      short8v ihh[4], ihl[4];
      if (l == 0) {
        ihh[0] = xh[st]; ihl[0] = xl[st];
        ihh[1] = short8v{}; ihh[2] = short8v{}; ihh[3] = short8v{};
        ihl[1] = short8v{}; ihl[2] = short8v{}; ihl[3] = short8v{};
      } else {
        const unsigned short* rbase = rbc + (st * BPS + rowl) * RC + kg * 8;
        ihh[0] = ld16_sys(rbase + 0);
        ihh[1] = ld16_sys(rbase + 32);
        ihh[2] = ld16_sys(rbase + 64);
        ihh[3] = ld16_sys(rbase + 96);
        ihl[0] = ld16_sys(rbase + PLANE + 0);
        ihl[1] = ld16_sys(rbase + PLANE + 32);
        ihl[2] = ld16_sys(rbase + PLANE + 64);
        ihl[3] = ld16_sys(rbase + PLANE + 96);
      }

      // hh fragments (LDS, hi + lo) — compiler-tracked lgkmcnt
      short8v ahh[4], alo[4];
#pragma unroll
      for (int kc = 0; kc < 4; ++kc) {
        ahh[kc] = *(const short8v*)&hHi[rowl][kc * 32 + kg * 8];
        alo[kc] = *(const short8v*)&hLo[rowl][kc * 32 + kg * 8];
      }

      f32x4 acc0 = {bias0, bias0, bias0, bias0};
      f32x4 acc1 = {bias1, bias1, bias1, bias1};
#pragma unroll
      for (int kc = 0; kc < 4; ++kc) {
        acc0 = __builtin_amdgcn_mfma_f32_16x16x32_bf16(ahh[kc], bhh0[kc], acc0, 0, 0, 0);
        acc1 = __builtin_amdgcn_mfma_f32_16x16x32_bf16(ahh[kc], bhh1[kc], acc1, 0, 0, 0);
        acc0 = __builtin_amdgcn_mfma_f32_16x16x32_bf16(alo[kc], bhh0[kc], acc0, 0, 0, 0);
        acc1 = __builtin_amdgcn_mfma_f32_16x16x32_bf16(alo[kc], bhh1[kc], acc1, 0, 0, 0);
      }

      // asm ring-load results are untracked by the compiler (rule #18):
      // drain vmcnt, then fence the scheduler before the consuming MFMAs.
      asm volatile("s_waitcnt vmcnt(0)" ::: "memory");
      __builtin_amdgcn_sched_barrier(0);

#pragma unroll
      for (int kc = 0; kc < 4; ++kc) {
        acc0 = __builtin_amdgcn_mfma_f32_16x16x32_bf16(ihh[kc], bih0[kc], acc0, 0, 0, 0);
        acc1 = __builtin_amdgcn_mfma_f32_16x16x32_bf16(ihh[kc], bih1[kc], acc1, 0, 0, 0);
        acc0 = __builtin_amdgcn_mfma_f32_16x16x32_bf16(ihl[kc], bih0[kc], acc0, 0, 0, 0);
        acc1 = __builtin_amdgcn_mfma_f32_16x16x32_bf16(ihl[kc], bih1[kc], acc1, 0, 0, 0);
      }

      // tanh + hi/lo split
      unsigned short nh0[4], nl0[4], nh1[4], nl1[4];
#pragma unroll
      for (int r = 0; r < 4; ++r) {
        float v0 = fast_tanh(acc0[r]);
        float v1 = fast_tanh(acc1[r]);
        nh0[r] = f2bf(v0); nl0[r] = f2bf(v0 - bf2f(nh0[r]));
        nh1[r] = f2bf(v1); nl1[r] = f2bf(v1 - bf2f(nh1[r]));
      }

      __syncthreads();  // all waves done reading hHi/hLo for this step

      // D layout (m89): col = lane&15, row = (lane>>4)*4 + reg
#pragma unroll
      for (int r = 0; r < 4; ++r) {
        const int m = kg * 4 + r;
        if (j0 < NH) { hHi[m][j0] = nh0[r]; hLo[m][j0] = nl0[r]; }
        if (j1 < NH) { hHi[m][j1] = nh1[r]; hLo[m][j1] = nl1[r]; }
      }
      __syncthreads();  // h(t) complete in LDS

      if (l < NL - 1) {
        // full-plane coherent ring copy: 256 thr x 8 ushorts = 16x128 (hi&lo)
        const int rr = tid >> 4;          // 0..15
        const int c8 = (tid & 15) * 8;    // 0..120
        unsigned short* dst = robc + (st * BPS + rr) * RC + c8;
        st16_sys(dst, *(const short8v*)&hHi[rr][c8]);
        st16_sys(dst + PLANE, *(const short8v*)&hLo[rr][c8]);
      } else {
        // fused FC (O=1): 16 lanes per batch row, shfl reduce
        const int r = tid >> 4, ks = tid & 15;
        float sum = 0.f;
        for (int k = ks; k < NH; k += 16)
          sum = fmaf(bf2f(hHi[r][k]) + bf2f(hLo[r][k]), fcwL[k], sum);
        sum += __shfl_xor(sum, 1);
        sum += __shfl_xor(sum, 2);
        sum += __shfl_xor(sum, 4);
        sum += __shfl_xor(sum, 8);
        if (ks == 0) out[(size_t)(b0 + r) * NT + t] = sum + fcb;
      }

      if (t == NT - 1) {
        for (int i = tid; i < BPS * NH; i += NTHR) {
          const int r = i / NH, j = i - r * NH;
          hfin[(size_t)l * NB * NH + (size_t)(b0 + r) * NH + j] =
              bf2f(hHi[r][j]) + bf2f(hLo[r][j]);
        }
      }
    }

    // ring stores (incl. inline-asm ones) must be at the coherence point
    // before the flag: explicit per-wave vmcnt drain, then block barrier.
    asm volatile("s_waitcnt vmcnt(0)" ::: "memory");
    __syncthreads();
    if (tid == 0) st_rlx(pme, (unsigned)(c + 1));
  }
}

extern "C" void kernel_launch(void* const* d_in, const int* in_sizes, int n_in,
                              void* d_out, int out_size, void* d_ws, size_t ws_size,
                              hipStream_t stream) {
  const float* x = (const float*)d_in[0];
  const float* hidden = (const float*)d_in[1];
  const float* w_ih0 = (const float*)d_in[2];
  const float* w_ihL = (const float*)d_in[3];
  const float* w_hh = (const float*)d_in[4];
  const float* b_ih = (const float*)d_in[5];
  const float* b_hh = (const float*)d_in[6];
  const float* fc_w = (const float*)d_in[7];
  const float* fc_b = (const float*)d_in[8];
  float* out = (float*)d_out;
  float* hfin = out + (size_t)NB * NT;  // out [B*T,1] then h_final [L,B,H]
  unsigned* prog = (unsigned*)d_ws;
  unsigned short* ring = (unsigned short*)((char*)d_ws + FLAGBYTES);

  const size_t per_d = (size_t)(NL - 1) * NS * RSLOT2 * 2;  // bytes per depth
  if (ws_size < FLAGBYTES + 2 * per_d) return;  // fail safe, no OOB
  int D = 16;
  while (D > 2 && FLAGBYTES + (size_t)D * per_d > ws_size) D >>= 1;

  zero_flags<<<8, 256, 0, stream>>>(prog);
  rnn_mfma<<<NL * NS, NTHR, 0, stream>>>(x, hidden, w_ih0, w_ihL, w_hh, b_ih,
                                         b_hh, fc_w, fc_b, out, hfin, prog,
                                         ring, D);
}

// Round 7
// 3974.184 us; speedup vs baseline: 1.4182x; 1.4182x over previous
//
#include <hip/hip_runtime.h>

#define NL 10   // layers
#define NB 64   // batch
#define NT 2048 // time steps
#define NI 14   // input features
#define NH 100  // hidden
#define NS 4    // batch slices
#define BPS 16  // batch rows per slice (= MFMA M)
#define CH 8    // timesteps per published chunk
#define NTC (NT / CH)
#define HSTR 136  // LDS h row stride in ushorts (272B)
#define RC 104    // ring row cols (bf16; cols 100..103 zero)
#define PLANE (CH * BPS * RC)  // ushorts per chunk slot = 13312 (26 KB)
#define NTHR 256
#define FLAGW 16
#define FLAGBYTES 8192
#define ABORT_IDX (NL * NS * FLAGW)
#define SPIN_CAP (1 << 18)

typedef __attribute__((ext_vector_type(8))) short short8v;  // 8 bf16 = 4 VGPR
typedef __attribute__((ext_vector_type(4))) float f32x4;

__device__ __forceinline__ unsigned ld_rlx(const unsigned* p) {
  return __hip_atomic_load(p, __ATOMIC_RELAXED, __HIP_MEMORY_SCOPE_AGENT);
}
__device__ __forceinline__ void st_rlx(unsigned* p, unsigned v) {
  __hip_atomic_store(p, v, __ATOMIC_RELAXED, __HIP_MEMORY_SCOPE_AGENT);
}
__device__ __forceinline__ unsigned short f2bf(float f) {
  unsigned u = __float_as_uint(f);
  return (unsigned short)((u + 0x7FFFu + ((u >> 16) & 1u)) >> 16);  // RNE
}
__device__ __forceinline__ float bf2f(unsigned short u) {
  return __uint_as_float((unsigned)u << 16);
}
__device__ __forceinline__ float fast_tanh(float v) {
  float e = __expf(2.f * v);
  return 1.f - 2.f / (e + 1.f);
}

// Device-coherent 16B ring accesses (bypass incoherent L1/L2; no wb/inv).
__device__ __forceinline__ short8v ld16_sys(const unsigned short* p) {
  short8v r;
  asm volatile("global_load_dwordx4 %0, %1, off sc0 sc1"
               : "=v"(r) : "v"(p) : "memory");
  return r;
}
__device__ __forceinline__ void st16_sys(unsigned short* p, short8v v) {
  asm volatile("global_store_dwordx4 %0, %1, off sc0 sc1"
               :: "v"(p), "v"(v) : "memory");
}

__device__ __forceinline__ int wait_ge(const unsigned* p, unsigned tgt,
                                       unsigned* abortf) {
  int iters = 0;
  while (ld_rlx(p) < tgt) {
    if (++iters > SPIN_CAP) { st_rlx(abortf, 1u); return 1; }
    if ((iters & 63) == 0 && ld_rlx(abortf) != 0) return 1;
    __builtin_amdgcn_s_sleep(2);
  }
  return 0;
}

__global__ void zero_flags(unsigned* p) {
  p[blockIdx.x * 256 + threadIdx.x] = 0u;
}

__global__ __launch_bounds__(NTHR, 1)
void rnn_mfma(const float* __restrict__ x, const float* __restrict__ hidden,
              const float* __restrict__ w_ih0, const float* __restrict__ w_ihL,
              const float* __restrict__ w_hh, const float* __restrict__ b_ih,
              const float* __restrict__ b_hh, const float* __restrict__ fc_w,
              const float* __restrict__ fc_b, float* __restrict__ out,
              float* __restrict__ hfin, unsigned* __restrict__ prog,
              unsigned short* __restrict__ ring, int D) {
  __shared__ unsigned short hHi[BPS][HSTR];  // h hi-plane, cols >=100 zero
  __shared__ unsigned short hLo[BPS][HSTR];  // h lo-plane (residual)
  __shared__ float fcwL[112];
  __shared__ int sAbort;

  const int bid = blockIdx.x;
  const int l = bid / NS;
  const int s = bid - l * NS;
  const int tid = threadIdx.x;
  const int b0 = s * BPS;
  const int w = tid >> 6;
  const int ln = tid & 63;
  const int rowl = ln & 15;      // A row / B col / D col index
  const int kg = (ln >> 4) & 3;  // k-group (8 k's per K=32 chunk)

  // ---- init LDS: h0 split hi/lo, fc weights ----
  for (int i = tid; i < BPS * HSTR; i += NTHR) {
    int r = i / HSTR, cc = i - r * HSTR;
    unsigned short hv = 0, lv = 0;
    if (cc < NH) {
      float f = hidden[(size_t)l * NB * NH + (size_t)(b0 + r) * NH + cc];
      hv = f2bf(f);
      lv = f2bf(f - bf2f(hv));
    }
    (&hHi[0][0])[i] = hv;
    (&hLo[0][0])[i] = lv;
  }
  for (int i = tid; i < 112; i += NTHR) fcwL[i] = (i < NH) ? fc_w[i] : 0.f;
  if (tid == 0) sAbort = 0;

  // ---- persistent weight B-fragments (wave w: cols 2w*16, (2w+1)*16) ----
  const int j0 = (w * 2) * 16 + rowl;
  const int j1 = (w * 2 + 1) * 16 + rowl;
  const float* Whh = w_hh + (size_t)l * NH * NH;
  const float* Wih = (l == 0) ? w_ih0 : (w_ihL + (size_t)(l - 1) * NH * NH);
  const int KI = (l == 0) ? NI : NH;

  short8v bhh0[4], bhh1[4], bih0[4], bih1[4];
#pragma unroll
  for (int kc = 0; kc < 4; ++kc) {
    short8v f0 = {}, f1 = {}, g0 = {}, g1 = {};
    const int kb = kc * 32 + kg * 8;
#pragma unroll
    for (int e = 0; e < 8; ++e) {
      const int k = kb + e;
      if (k < NH) {
        if (j0 < NH) f0[e] = (short)f2bf(Whh[j0 * NH + k]);
        if (j1 < NH) f1[e] = (short)f2bf(Whh[j1 * NH + k]);
      }
      if (k < KI) {
        if (j0 < NH) g0[e] = (short)f2bf(Wih[j0 * KI + k]);
        if (j1 < NH) g1[e] = (short)f2bf(Wih[j1 * KI + k]);
      }
    }
    bhh0[kc] = f0; bhh1[kc] = f1; bih0[kc] = g0; bih1[kc] = g1;
  }
  const float bias0 = (j0 < NH) ? b_ih[l * NH + j0] + b_hh[l * NH + j0] : 0.f;
  const float bias1 = (j1 < NH) ? b_ih[l * NH + j1] + b_hh[l * NH + j1] : 0.f;
  const float fcb = fc_b[0];

  const unsigned* pin = prog + ((l > 0 ? (l - 1) * NS + s : 0)) * FLAGW;
  const unsigned* pout = prog + ((l < NL - 1 ? (l + 1) * NS + s : 0)) * FLAGW;
  unsigned* pme = prog + (l * NS + s) * FLAGW;
  unsigned* abortf = prog + ABORT_IDX;

  const unsigned short* rin =
      ring + (size_t)(l > 0 ? (l - 1) * NS + s : 0) * D * PLANE;
  unsigned short* rout = ring + (size_t)(l * NS + s) * D * PLANE;

  __syncthreads();

  for (int c = 0; c < NTC; ++c) {
    // ---- chunk-level sync (relaxed polls; sc0sc1 data coherence) ----
    if (tid == 0) {
      int ab = 0;
      if (l > 0) ab |= wait_ge(pin, (unsigned)(c + 1), abortf);
      if (!ab && l < NL - 1 && c >= D)
        ab |= wait_ge(pout, (unsigned)(c - D + 1), abortf);
      sAbort = ab;
    }
    __syncthreads();
    if (sAbort) return;

    // ---- stage the WHOLE chunk's input fragments into VGPRs ----
    // l==0: ich[st][0]=x_hi, ich[st][1]=x_lo (NI=14 fits in kc=0).
    // l>0 : 32 coherent ring loads, ONE vmcnt wait (below, under hh chain).
    short8v ich[CH][4];
    if (l == 0) {
#pragma unroll
      for (int st = 0; st < CH; ++st) {
        short8v hh = {}, ll = {};
        const float* xp =
            x + (size_t)(b0 + rowl) * (NT * NI) + (size_t)(c * CH + st) * NI;
        if (kg < 2) {
#pragma unroll
          for (int e = 0; e < 8; ++e) {
            const int k = kg * 8 + e;
            if (k < NI) {
              float f = xp[k];
              unsigned short hu = f2bf(f);
              hh[e] = (short)hu;
              ll[e] = (short)f2bf(f - bf2f(hu));
            }
          }
        }
        ich[st][0] = hh; ich[st][1] = ll;
        ich[st][2] = short8v{}; ich[st][3] = short8v{};
      }
    } else {
      const unsigned short* rbc = rin + (size_t)(c % D) * PLANE;
#pragma unroll
      for (int st = 0; st < CH; ++st) {
        const unsigned short* rbase = rbc + (st * BPS + rowl) * RC + kg * 8;
#pragma unroll
        for (int kc = 0; kc < 4; ++kc)
          ich[st][kc] = ld16_sys(rbase + kc * 32);
      }
    }

    unsigned short* robc = rout + (size_t)(c % D) * PLANE;

    // ---- CH recurrent steps ----
#pragma unroll
    for (int st = 0; st < CH; ++st) {
      const int t = c * CH + st;

      short8v ahh[4], alo[4];
#pragma unroll
      for (int kc = 0; kc < 4; ++kc) {
        ahh[kc] = *(const short8v*)&hHi[rowl][kc * 32 + kg * 8];
        alo[kc] = *(const short8v*)&hLo[rowl][kc * 32 + kg * 8];
      }

      f32x4 acc0 = {bias0, bias0, bias0, bias0};
      f32x4 acc1 = {bias1, bias1, bias1, bias1};
#pragma unroll
      for (int kc = 0; kc < 4; ++kc) {
        acc0 = __builtin_amdgcn_mfma_f32_16x16x32_bf16(ahh[kc], bhh0[kc], acc0, 0, 0, 0);
        acc1 = __builtin_amdgcn_mfma_f32_16x16x32_bf16(ahh[kc], bhh1[kc], acc1, 0, 0, 0);
        acc0 = __builtin_amdgcn_mfma_f32_16x16x32_bf16(alo[kc], bhh0[kc], acc0, 0, 0, 0);
        acc1 = __builtin_amdgcn_mfma_f32_16x16x32_bf16(alo[kc], bhh1[kc], acc1, 0, 0, 0);
      }

      if (st == 0 && l > 0) {
        // asm ring-loads are compiler-untracked (rule #18): drain once for
        // the whole chunk, fence the scheduler, then consume.
        asm volatile("s_waitcnt vmcnt(0)" ::: "memory");
        __builtin_amdgcn_sched_barrier(0);
      }

      if (l == 0) {
        acc0 = __builtin_amdgcn_mfma_f32_16x16x32_bf16(ich[st][0], bih0[0], acc0, 0, 0, 0);
        acc1 = __builtin_amdgcn_mfma_f32_16x16x32_bf16(ich[st][0], bih1[0], acc1, 0, 0, 0);
        acc0 = __builtin_amdgcn_mfma_f32_16x16x32_bf16(ich[st][1], bih0[0], acc0, 0, 0, 0);
        acc1 = __builtin_amdgcn_mfma_f32_16x16x32_bf16(ich[st][1], bih1[0], acc1, 0, 0, 0);
      } else {
#pragma unroll
        for (int kc = 0; kc < 4; ++kc) {
          acc0 = __builtin_amdgcn_mfma_f32_16x16x32_bf16(ich[st][kc], bih0[kc], acc0, 0, 0, 0);
          acc1 = __builtin_amdgcn_mfma_f32_16x16x32_bf16(ich[st][kc], bih1[kc], acc1, 0, 0, 0);
        }
      }

      // tanh + hi/lo split
      unsigned short nh0[4], nl0[4], nh1[4], nl1[4];
#pragma unroll
      for (int r = 0; r < 4; ++r) {
        float v0 = fast_tanh(acc0[r]);
        float v1 = fast_tanh(acc1[r]);
        nh0[r] = f2bf(v0); nl0[r] = f2bf(v0 - bf2f(nh0[r]));
        nh1[r] = f2bf(v1); nl1[r] = f2bf(v1 - bf2f(nh1[r]));
      }

      __syncthreads();  // all waves done reading hHi/hLo for this step

      // D layout (m89): col = lane&15, row = (lane>>4)*4 + reg
#pragma unroll
      for (int r = 0; r < 4; ++r) {
        const int m = kg * 4 + r;
        if (j0 < NH) { hHi[m][j0] = nh0[r]; hLo[m][j0] = nl0[r]; }
        if (j1 < NH) { hHi[m][j1] = nh1[r]; hLo[m][j1] = nl1[r]; }
      }
      __syncthreads();  // h(t) complete in LDS

      if (l < NL - 1) {
        // ring store: 208 threads x 8 ushorts = 16 rows x 104 cols (hi only)
        if (tid < BPS * (RC / 8)) {
          const int rr = tid / 13, c8 = (tid - rr * 13) * 8;
          st16_sys(robc + (st * BPS + rr) * RC + c8,
                   *(const short8v*)&hHi[rr][c8]);
        }
      } else {
        // fused FC (O=1): 16 lanes per batch row, shfl reduce
        const int r = tid >> 4, ks = tid & 15;
        float sum = 0.f;
        for (int k = ks; k < NH; k += 16)
          sum = fmaf(bf2f(hHi[r][k]) + bf2f(hLo[r][k]), fcwL[k], sum);
        sum += __shfl_xor(sum, 1);
        sum += __shfl_xor(sum, 2);
        sum += __shfl_xor(sum, 4);
        sum += __shfl_xor(sum, 8);
        if (ks == 0) out[(size_t)(b0 + r) * NT + t] = sum + fcb;
      }

      if (t == NT - 1) {
        for (int i = tid; i < BPS * NH; i += NTHR) {
          const int r = i / NH, j = i - r * NH;
          hfin[(size_t)l * NB * NH + (size_t)(b0 + r) * NH + j] =
              bf2f(hHi[r][j]) + bf2f(hLo[r][j]);
        }
      }
    }

    // drain ring stores to the coherence point before publishing
    asm volatile("s_waitcnt vmcnt(0)" ::: "memory");
    __syncthreads();
    if (tid == 0) st_rlx(pme, (unsigned)(c + 1));
  }
}

extern "C" void kernel_launch(void* const* d_in, const int* in_sizes, int n_in,
                              void* d_out, int out_size, void* d_ws, size_t ws_size,
                              hipStream_t stream) {
  const float* x = (const float*)d_in[0];
  const float* hidden = (const float*)d_in[1];
  const float* w_ih0 = (const float*)d_in[2];
  const float* w_ihL = (const float*)d_in[3];
  const float* w_hh = (const float*)d_in[4];
  const float* b_ih = (const float*)d_in[5];
  const float* b_hh = (const float*)d_in[6];
  const float* fc_w = (const float*)d_in[7];
  const float* fc_b = (const float*)d_in[8];
  float* out = (float*)d_out;
  float* hfin = out + (size_t)NB * NT;  // out [B*T,1] then h_final [L,B,H]
  unsigned* prog = (unsigned*)d_ws;
  unsigned short* ring = (unsigned short*)((char*)d_ws + FLAGBYTES);

  // slot = 26 KB; per-depth = 36 slots; +128B slack for kc=3 tail over-read
  const size_t per_d = (size_t)(NL - 1) * NS * PLANE * 2;
  if (ws_size < FLAGBYTES + per_d + 128) return;  // fail safe, no OOB
  int D = 32;
  while (D > 1 && FLAGBYTES + (size_t)D * per_d + 128 > ws_size) D >>= 1;

  zero_flags<<<8, 256, 0, stream>>>(prog);
  rnn_mfma<<<NL * NS, NTHR, 0, stream>>>(x, hidden, w_ih0, w_ihL, w_hh, b_ih,
                                         b_hh, fc_w, fc_b, out, hfin, prog,
                                         ring, D);
}

// Round 8
// 3545.484 us; speedup vs baseline: 1.5897x; 1.1209x over previous
//
#include <hip/hip_runtime.h>

#define NL 10   // layers
#define NB 64   // batch
#define NT 2048 // time steps
#define NI 14   // input features
#define NH 100  // hidden
#define NS 4    // batch slices
#define BPS 16  // batch rows per slice (= MFMA M)
#define CH 8    // timesteps per published chunk
#define NTC (NT / CH)
#define HSTR 136  // LDS h row stride in ushorts (272B)
#define RC 104    // ring row cols (bf16; cols 100..103 zero)
#define PLANE (CH * BPS * RC)  // ushorts per chunk slot = 13312 (26 KB)
#define NTHR 448  // 7 waves: one 16-col output tile each (7*16=112 >= 100)
#define NW 7
#define FLAGW 16
#define FLAGBYTES 8192
#define ABORT_IDX (NL * NS * FLAGW)
#define SPIN_CAP (1 << 18)

typedef __attribute__((ext_vector_type(8))) short short8v;  // 8 bf16 = 4 VGPR
typedef __attribute__((ext_vector_type(4))) float f32x4;

__device__ __forceinline__ unsigned ld_rlx(const unsigned* p) {
  return __hip_atomic_load(p, __ATOMIC_RELAXED, __HIP_MEMORY_SCOPE_AGENT);
}
__device__ __forceinline__ void st_rlx(unsigned* p, unsigned v) {
  __hip_atomic_store(p, v, __ATOMIC_RELAXED, __HIP_MEMORY_SCOPE_AGENT);
}
__device__ __forceinline__ unsigned short f2bf(float f) {
  unsigned u = __float_as_uint(f);
  return (unsigned short)((u + 0x7FFFu + ((u >> 16) & 1u)) >> 16);  // RNE
}
__device__ __forceinline__ float bf2f(unsigned short u) {
  return __uint_as_float((unsigned)u << 16);
}
__device__ __forceinline__ float fast_tanh(float v) {
  float e = __expf(2.f * v);
  return 1.f - 2.f / (e + 1.f);
}

// Device-coherent 16B ring accesses (bypass incoherent L1/L2; no wb/inv).
__device__ __forceinline__ short8v ld16_sys(const unsigned short* p) {
  short8v r;
  asm volatile("global_load_dwordx4 %0, %1, off sc0 sc1"
               : "=v"(r) : "v"(p) : "memory");
  return r;
}
__device__ __forceinline__ void st16_sys(unsigned short* p, short8v v) {
  asm volatile("global_store_dwordx4 %0, %1, off sc0 sc1"
               :: "v"(p), "v"(v) : "memory");
}

__device__ __forceinline__ int wait_ge(const unsigned* p, unsigned tgt,
                                       unsigned* abortf) {
  int iters = 0;
  while (ld_rlx(p) < tgt) {
    if (++iters > SPIN_CAP) { st_rlx(abortf, 1u); return 1; }
    if ((iters & 63) == 0 && ld_rlx(abortf) != 0) return 1;
    __builtin_amdgcn_s_sleep(2);
  }
  return 0;
}

__global__ void zero_flags(unsigned* p) {
  p[blockIdx.x * 256 + threadIdx.x] = 0u;
}

__global__ __launch_bounds__(NTHR, 2)  // 2 waves/SIMD: cap VGPR at 256
void rnn_mfma(const float* __restrict__ x, const float* __restrict__ hidden,
              const float* __restrict__ w_ih0, const float* __restrict__ w_ihL,
              const float* __restrict__ w_hh, const float* __restrict__ b_ih,
              const float* __restrict__ b_hh, const float* __restrict__ fc_w,
              const float* __restrict__ fc_b, float* __restrict__ out,
              float* __restrict__ hfin, unsigned* __restrict__ prog,
              unsigned short* __restrict__ ring, int D) {
  __shared__ unsigned short hHi[BPS][HSTR];  // h hi-plane, cols >=100 zero
  __shared__ unsigned short hLo[BPS][HSTR];  // h lo-plane (residual)
  __shared__ float fcwL[112];
  __shared__ int sAbort;

  const int bid = blockIdx.x;
  const int l = bid / NS;
  const int s = bid - l * NS;
  const int tid = threadIdx.x;
  const int b0 = s * BPS;
  const int w = tid >> 6;        // wave id 0..6
  const int ln = tid & 63;
  const int rowl = ln & 15;      // A row / B col / D col index
  const int kg = (ln >> 4) & 3;  // k-group (8 k's per K=32 chunk)

  // ---- init LDS: h0 split hi/lo, fc weights ----
  for (int i = tid; i < BPS * HSTR; i += NTHR) {
    int r = i / HSTR, cc = i - r * HSTR;
    unsigned short hv = 0, lv = 0;
    if (cc < NH) {
      float f = hidden[(size_t)l * NB * NH + (size_t)(b0 + r) * NH + cc];
      hv = f2bf(f);
      lv = f2bf(f - bf2f(hv));
    }
    (&hHi[0][0])[i] = hv;
    (&hLo[0][0])[i] = lv;
  }
  for (int i = tid; i < 112; i += NTHR) fcwL[i] = (i < NH) ? fc_w[i] : 0.f;
  if (tid == 0) sAbort = 0;

  // ---- persistent weight B-fragments: wave w owns output cols w*16..w*16+15 ----
  const int j = w * 16 + rowl;
  const float* Whh = w_hh + (size_t)l * NH * NH;
  const float* Wih = (l == 0) ? w_ih0 : (w_ihL + (size_t)(l - 1) * NH * NH);
  const int KI = (l == 0) ? NI : NH;

  short8v bhh[4], bih[4];
#pragma unroll
  for (int kc = 0; kc < 4; ++kc) {
    short8v f0 = {}, g0 = {};
    const int kb = kc * 32 + kg * 8;
    if (j < NH) {
#pragma unroll
      for (int e = 0; e < 8; ++e) {
        const int k = kb + e;
        if (k < NH) f0[e] = (short)f2bf(Whh[j * NH + k]);
        if (k < KI) g0[e] = (short)f2bf(Wih[j * KI + k]);
      }
    }
    bhh[kc] = f0; bih[kc] = g0;
  }
  const float bias = (j < NH) ? b_ih[l * NH + j] + b_hh[l * NH + j] : 0.f;
  const float fcb = fc_b[0];

  const unsigned* pin = prog + ((l > 0 ? (l - 1) * NS + s : 0)) * FLAGW;
  const unsigned* pout = prog + ((l < NL - 1 ? (l + 1) * NS + s : 0)) * FLAGW;
  unsigned* pme = prog + (l * NS + s) * FLAGW;
  unsigned* abortf = prog + ABORT_IDX;

  const unsigned short* rin =
      ring + (size_t)(l > 0 ? (l - 1) * NS + s : 0) * D * PLANE;
  unsigned short* rout = ring + (size_t)(l * NS + s) * D * PLANE;

  __syncthreads();

  for (int c = 0; c < NTC; ++c) {
    // ---- chunk-level sync (relaxed polls; sc0sc1 data coherence) ----
    if (tid == 0) {
      int ab = 0;
      if (l > 0) ab |= wait_ge(pin, (unsigned)(c + 1), abortf);
      if (!ab && l < NL - 1 && c >= D)
        ab |= wait_ge(pout, (unsigned)(c - D + 1), abortf);
      sAbort = ab;
    }
    __syncthreads();
    if (sAbort) return;

    // ---- layer-0: stage x hi/lo for the chunk (normal cached loads) ----
    short8v xh[CH], xl[CH];
    if (l == 0 && w < NW) {
#pragma unroll
      for (int st = 0; st < CH; ++st) {
        short8v hh = {}, ll = {};
        const float* xp =
            x + (size_t)(b0 + rowl) * (NT * NI) + (size_t)(c * CH + st) * NI;
        if (kg < 2) {
#pragma unroll
          for (int e = 0; e < 8; ++e) {
            const int k = kg * 8 + e;
            if (k < NI) {
              float f = xp[k];
              unsigned short hu = f2bf(f);
              hh[e] = (short)hu;
              ll[e] = (short)f2bf(f - bf2f(hu));
            }
          }
        }
        xh[st] = hh; xl[st] = ll;
      }
    }

    const unsigned short* rbc = rin + (size_t)(c % D) * PLANE;
    unsigned short* robc = rout + (size_t)(c % D) * PLANE;

    // ---- CH recurrent steps ----
#pragma unroll
    for (int st = 0; st < CH; ++st) {
      const int t = c * CH + st;

      unsigned short nh[4], nl[4];
      if (w < NW) {
        // JIT ring loads for THIS step (4x16B); latency hides under hh chains
        short8v ic0, ic1, ic2, ic3;
        if (l > 0) {
          const unsigned short* rbase = rbc + (st * BPS + rowl) * RC + kg * 8;
          ic0 = ld16_sys(rbase + 0);
          ic1 = ld16_sys(rbase + 32);
          ic2 = ld16_sys(rbase + 64);
          ic3 = ld16_sys(rbase + 96);
        }

        short8v ahh[4], alo[4];
#pragma unroll
        for (int kc = 0; kc < 4; ++kc) {
          ahh[kc] = *(const short8v*)&hHi[rowl][kc * 32 + kg * 8];
          alo[kc] = *(const short8v*)&hLo[rowl][kc * 32 + kg * 8];
        }

        // two parallel 4-deep hh chains (hi, lo)
        f32x4 acch = {0.f, 0.f, 0.f, 0.f};
        f32x4 accl = {0.f, 0.f, 0.f, 0.f};
#pragma unroll
        for (int kc = 0; kc < 4; ++kc) {
          acch = __builtin_amdgcn_mfma_f32_16x16x32_bf16(ahh[kc], bhh[kc], acch, 0, 0, 0);
          accl = __builtin_amdgcn_mfma_f32_16x16x32_bf16(alo[kc], bhh[kc], accl, 0, 0, 0);
        }

        // ih chain (parallel accumulator)
        f32x4 acci = {0.f, 0.f, 0.f, 0.f};
        if (l == 0) {
          acci = __builtin_amdgcn_mfma_f32_16x16x32_bf16(xh[st], bih[0], acci, 0, 0, 0);
          acci = __builtin_amdgcn_mfma_f32_16x16x32_bf16(xl[st], bih[0], acci, 0, 0, 0);
        } else {
          // asm loads are compiler-untracked (rule #18): drain + sched fence
          asm volatile("s_waitcnt vmcnt(0)" ::: "memory");
          __builtin_amdgcn_sched_barrier(0);
          acci = __builtin_amdgcn_mfma_f32_16x16x32_bf16(ic0, bih[0], acci, 0, 0, 0);
          acci = __builtin_amdgcn_mfma_f32_16x16x32_bf16(ic1, bih[1], acci, 0, 0, 0);
          acci = __builtin_amdgcn_mfma_f32_16x16x32_bf16(ic2, bih[2], acci, 0, 0, 0);
          acci = __builtin_amdgcn_mfma_f32_16x16x32_bf16(ic3, bih[3], acci, 0, 0, 0);
        }

        // merge + tanh + hi/lo split
#pragma unroll
        for (int r = 0; r < 4; ++r) {
          float v = fast_tanh(acch[r] + accl[r] + acci[r] + bias);
          nh[r] = f2bf(v);
          nl[r] = f2bf(v - bf2f(nh[r]));
        }
      }

      __syncthreads();  // all waves done reading hHi/hLo for this step

      // D layout (m89): col = lane&15, row = (lane>>4)*4 + reg
      if (w < NW && j < NH) {
#pragma unroll
        for (int r = 0; r < 4; ++r) {
          const int m = kg * 4 + r;
          hHi[m][j] = nh[r];
          hLo[m][j] = nl[r];
        }
      }
      __syncthreads();  // h(t) complete in LDS

      if (l < NL - 1) {
        // ring store: 208 threads x 8 ushorts = 16 rows x 104 cols (hi only)
        if (tid < BPS * (RC / 8)) {
          const int rr = tid / 13, c8 = (tid - rr * 13) * 8;
          st16_sys(robc + (st * BPS + rr) * RC + c8,
                   *(const short8v*)&hHi[rr][c8]);
        }
      } else {
        // fused FC (O=1): 16 lanes per batch row, shfl reduce
        if (tid < 256) {
          const int r = tid >> 4, ks = tid & 15;
          float sum = 0.f;
          for (int k = ks; k < NH; k += 16)
            sum = fmaf(bf2f(hHi[r][k]) + bf2f(hLo[r][k]), fcwL[k], sum);
          sum += __shfl_xor(sum, 1);
          sum += __shfl_xor(sum, 2);
          sum += __shfl_xor(sum, 4);
          sum += __shfl_xor(sum, 8);
          if (ks == 0) out[(size_t)(b0 + r) * NT + t] = sum + fcb;
        }
      }

      if (t == NT - 1) {
        for (int i = tid; i < BPS * NH; i += NTHR) {
          const int r = i / NH, jj = i - r * NH;
          hfin[(size_t)l * NB * NH + (size_t)(b0 + r) * NH + jj] =
              bf2f(hHi[r][jj]) + bf2f(hLo[r][jj]);
        }
      }
    }

    // drain ring stores to the coherence point before publishing
    asm volatile("s_waitcnt vmcnt(0)" ::: "memory");
    __syncthreads();
    if (tid == 0) st_rlx(pme, (unsigned)(c + 1));
  }
}

extern "C" void kernel_launch(void* const* d_in, const int* in_sizes, int n_in,
                              void* d_out, int out_size, void* d_ws, size_t ws_size,
                              hipStream_t stream) {
  const float* x = (const float*)d_in[0];
  const float* hidden = (const float*)d_in[1];
  const float* w_ih0 = (const float*)d_in[2];
  const float* w_ihL = (const float*)d_in[3];
  const float* w_hh = (const float*)d_in[4];
  const float* b_ih = (const float*)d_in[5];
  const float* b_hh = (const float*)d_in[6];
  const float* fc_w = (const float*)d_in[7];
  const float* fc_b = (const float*)d_in[8];
  float* out = (float*)d_out;
  float* hfin = out + (size_t)NB * NT;  // out [B*T,1] then h_final [L,B,H]
  unsigned* prog = (unsigned*)d_ws;
  unsigned short* ring = (unsigned short*)((char*)d_ws + FLAGBYTES);

  // slot = 26 KB; per-depth = 36 slots; +128B slack for kc=3 tail over-read
  const size_t per_d = (size_t)(NL - 1) * NS * PLANE * 2;
  if (ws_size < FLAGBYTES + per_d + 128) return;  // fail safe, no OOB
  int D = 32;
  while (D > 1 && FLAGBYTES + (size_t)D * per_d + 128 > ws_size) D >>= 1;

  zero_flags<<<8, 256, 0, stream>>>(prog);
  rnn_mfma<<<NL * NS, NTHR, 0, stream>>>(x, hidden, w_ih0, w_ihL, w_hh, b_ih,
                                         b_hh, fc_w, fc_b, out, hfin, prog,
                                         ring, D);
}

// Round 9
// 3265.144 us; speedup vs baseline: 1.7262x; 1.0859x over previous
//
#include <hip/hip_runtime.h>

#define NL 10   // layers
#define NB 64   // batch
#define NT 2048 // time steps
#define NI 14   // input features
#define NH 100  // hidden
#define NS 4    // batch slices
#define BPS 16  // batch rows per slice (= MFMA M)
#define CH 8    // timesteps per published chunk
#define NTC (NT / CH)
#define HSTR 144  // LDS h row stride (288B: 72 dwords = 8 mod 32 -> conflict-free writes)
#define RC 104    // ring row cols (bf16; cols 100..103 zero)
#define PLANE (CH * BPS * RC)  // ushorts per chunk slot = 13312 (26 KB)
#define NTHR 512  // 7 compute waves + 1 comms wave
#define NW 7
#define FLAGW 16
#define FLAGBYTES 8192
#define ABORT_IDX (NL * NS * FLAGW)
#define SPIN_CAP (1 << 18)

typedef __attribute__((ext_vector_type(8))) short short8v;  // 8 bf16 = 4 VGPR
typedef __attribute__((ext_vector_type(4))) float f32x4;

__device__ __forceinline__ unsigned ld_rlx(const unsigned* p) {
  return __hip_atomic_load(p, __ATOMIC_RELAXED, __HIP_MEMORY_SCOPE_AGENT);
}
__device__ __forceinline__ void st_rlx(unsigned* p, unsigned v) {
  __hip_atomic_store(p, v, __ATOMIC_RELAXED, __HIP_MEMORY_SCOPE_AGENT);
}
__device__ __forceinline__ unsigned short f2bf(float f) {
  unsigned u = __float_as_uint(f);
  return (unsigned short)((u + 0x7FFFu + ((u >> 16) & 1u)) >> 16);  // RNE
}
__device__ __forceinline__ float bf2f(unsigned short u) {
  return __uint_as_float((unsigned)u << 16);
}
__device__ __forceinline__ float fast_tanh(float v) {
  float e = __expf(2.f * v);
  return 1.f - 2.f / (e + 1.f);
}

// DEVICE-scope (sc1) ring accesses: bypass incoherent per-XCD L1/L2, are
// cached & coherent at the die-level L3. (sc0+sc1 = SYSTEM scope = HBM
// write-through -- that was round 8's 240 MB WRITE_SIZE.)
__device__ __forceinline__ short8v ld16_dev(const unsigned short* p) {
  short8v r;
  asm volatile("global_load_dwordx4 %0, %1, off sc1" : "=v"(r) : "v"(p));
  return r;
}
__device__ __forceinline__ void st16_dev(unsigned short* p, short8v v) {
  asm volatile("global_store_dwordx4 %0, %1, off sc1" :: "v"(p), "v"(v) : "memory");
}

__device__ __forceinline__ int wait_ge(const unsigned* p, unsigned tgt,
                                       unsigned* abortf) {
  int iters = 0;
  while (ld_rlx(p) < tgt) {
    if (++iters > SPIN_CAP) { st_rlx(abortf, 1u); return 1; }
    if ((iters & 63) == 0 && ld_rlx(abortf) != 0) return 1;
    __builtin_amdgcn_s_sleep(2);
  }
  return 0;
}

__global__ void zero_flags(unsigned* p) {
  p[blockIdx.x * 256 + threadIdx.x] = 0u;
}

__global__ __launch_bounds__(NTHR, 2)
void rnn_mfma(const float* __restrict__ x, const float* __restrict__ hidden,
              const float* __restrict__ w_ih0, const float* __restrict__ w_ihL,
              const float* __restrict__ w_hh, const float* __restrict__ b_ih,
              const float* __restrict__ b_hh, const float* __restrict__ fc_w,
              const float* __restrict__ fc_b, float* __restrict__ out,
              float* __restrict__ hfin, unsigned* __restrict__ prog,
              unsigned short* __restrict__ ring, int D) {
  __shared__ unsigned short hHi[2][BPS][HSTR];  // ping-pong h hi-plane
  __shared__ unsigned short hLo[2][BPS][HSTR];  // ping-pong h lo-plane
  __shared__ float fcwL[128];
  __shared__ int sAbort;
  __shared__ int sReadyC;  // highest chunk whose input/slot is verified

  const int bid = blockIdx.x;
  const int l = bid / NS;
  const int s = bid - l * NS;
  const int tid = threadIdx.x;
  const int b0 = s * BPS;
  const int w = tid >> 6;        // 0..6 compute, 7 comms
  const int ln = tid & 63;
  const int rowl = ln & 15;
  const int kg = (ln >> 4) & 3;

  // ---- init LDS: zero both buffers, h0 into buf0; fc weights ----
  for (int i = tid; i < 2 * BPS * HSTR; i += NTHR) {
    const int buf = i / (BPS * HSTR), rem = i - buf * (BPS * HSTR);
    const int r = rem / HSTR, cc = rem - r * HSTR;
    unsigned short hv = 0, lv = 0;
    if (buf == 0 && cc < NH) {
      float f = hidden[(size_t)l * NB * NH + (size_t)(b0 + r) * NH + cc];
      hv = f2bf(f);
      lv = f2bf(f - bf2f(hv));
    }
    (&hHi[0][0][0])[i] = hv;
    (&hLo[0][0][0])[i] = lv;
  }
  for (int i = tid; i < 128; i += NTHR) fcwL[i] = (i < NH) ? fc_w[i] : 0.f;
  if (tid == 0) { sAbort = 0; sReadyC = -1; }

  // ---- persistent weight B-fragments (compute waves only; comms j>=NH) ----
  const int j = w * 16 + rowl;
  const float* Whh = w_hh + (size_t)l * NH * NH;
  const float* Wih = (l == 0) ? w_ih0 : (w_ihL + (size_t)(l - 1) * NH * NH);
  const int KI = (l == 0) ? NI : NH;

  short8v bhh[4], bih[4];
#pragma unroll
  for (int kc = 0; kc < 4; ++kc) {
    short8v f0 = {}, g0 = {};
    const int kb = kc * 32 + kg * 8;
    if (j < NH) {
#pragma unroll
      for (int e = 0; e < 8; ++e) {
        const int k = kb + e;
        if (k < NH) f0[e] = (short)f2bf(Whh[j * NH + k]);
        if (k < KI) g0[e] = (short)f2bf(Wih[j * KI + k]);
      }
    }
    bhh[kc] = f0; bih[kc] = g0;
  }
  const float bias = (j < NH) ? b_ih[l * NH + j] + b_hh[l * NH + j] : 0.f;
  const float fcb = fc_b[0];

  const unsigned* pin = prog + ((l > 0 ? (l - 1) * NS + s : 0)) * FLAGW;
  const unsigned* pout = prog + ((l < NL - 1 ? (l + 1) * NS + s : 0)) * FLAGW;
  unsigned* pme = prog + (l * NS + s) * FLAGW;
  unsigned* abortf = prog + ABORT_IDX;

  const unsigned short* rin =
      ring + (size_t)(l > 0 ? (l - 1) * NS + s : 0) * D * PLANE;
  unsigned short* rout = ring + (size_t)(l * NS + s) * D * PLANE;

  __syncthreads();

  // comms wave: preload FC weight quarter into registers (static-indexed)
  float fcreg[32];
  if (w == NW && l == NL - 1) {
    const int q = ln & 3;
#pragma unroll
    for (int k = 0; k < 32; ++k) fcreg[k] = fcwL[q * 32 + k];
  }

  // ---- chunk-0 readiness (blocking, watchdogged) ----
  if (tid == 0) {
    int ab = 0;
    if (l > 0) ab = wait_ge(pin, 1u, abortf);
    if (ab) sAbort = 1; else sReadyC = 0;
  }
  __syncthreads();
  if (sAbort) return;

  bool ready = false;  // comms-local: chunk c+1 verified?

  for (int c = 0; c < NTC; ++c) {
    const unsigned short* rbc = rin + (size_t)(c % D) * PLANE;
    unsigned short* robc = rout + (size_t)(c % D) * PLANE;

    // ---- layer-0: stage x hi/lo for the chunk (compiler-tracked loads) ----
    short8v xh[CH], xl[CH];
    if (l == 0 && w < NW) {
#pragma unroll
      for (int st = 0; st < CH; ++st) {
        short8v hh = {}, ll = {};
        const float* xp =
            x + (size_t)(b0 + rowl) * (NT * NI) + (size_t)(c * CH + st) * NI;
        if (kg < 2) {
#pragma unroll
          for (int e = 0; e < 8; ++e) {
            const int k = kg * 8 + e;
            if (k < NI) {
              float f = xp[k];
              unsigned short hu = f2bf(f);
              hh[e] = (short)hu;
              ll[e] = (short)f2bf(f - bf2f(hu));
            }
          }
        }
        xh[st] = hh; xl[st] = ll;
      }
    }

    short8v icA0, icA1, icA2, icA3, icB0, icB1, icB2, icB3;

#pragma unroll
    for (int st = 0; st < CH; ++st) {
      if (w < NW) {
        // ---- compute wave ----
        if (l > 0) {
          // prefetch: set for step st+1 (A even steps, B odd steps)
          if (st == 0) {
            const unsigned short* r0 = rbc + (0 * BPS + rowl) * RC + kg * 8;
            icA0 = ld16_dev(r0 + 0);  icA1 = ld16_dev(r0 + 32);
            icA2 = ld16_dev(r0 + 64); icA3 = ld16_dev(r0 + 96);
            const unsigned short* r1 = rbc + (1 * BPS + rowl) * RC + kg * 8;
            icB0 = ld16_dev(r1 + 0);  icB1 = ld16_dev(r1 + 32);
            icB2 = ld16_dev(r1 + 64); icB3 = ld16_dev(r1 + 96);
          } else if (st < CH - 1) {
            const unsigned short* rn = rbc + ((st + 1) * BPS + rowl) * RC + kg * 8;
            if (st & 1) {  // next step even -> A
              icA0 = ld16_dev(rn + 0);  icA1 = ld16_dev(rn + 32);
              icA2 = ld16_dev(rn + 64); icA3 = ld16_dev(rn + 96);
            } else {       // next step odd -> B
              icB0 = ld16_dev(rn + 0);  icB1 = ld16_dev(rn + 32);
              icB2 = ld16_dev(rn + 64); icB3 = ld16_dev(rn + 96);
            }
          }
        }

        const int rb = st & 1;  // read buffer
        short8v ahh[4], alo[4];
#pragma unroll
        for (int kc = 0; kc < 4; ++kc) {
          ahh[kc] = *(const short8v*)&hHi[rb][rowl][kc * 32 + kg * 8];
          alo[kc] = *(const short8v*)&hLo[rb][rowl][kc * 32 + kg * 8];
        }

        f32x4 acch = {0.f, 0.f, 0.f, 0.f};
        f32x4 accl = {0.f, 0.f, 0.f, 0.f};
#pragma unroll
        for (int kc = 0; kc < 4; ++kc) {
          acch = __builtin_amdgcn_mfma_f32_16x16x32_bf16(ahh[kc], bhh[kc], acch, 0, 0, 0);
          accl = __builtin_amdgcn_mfma_f32_16x16x32_bf16(alo[kc], bhh[kc], accl, 0, 0, 0);
        }

        f32x4 acci = {0.f, 0.f, 0.f, 0.f};
        if (l == 0) {
          acci = __builtin_amdgcn_mfma_f32_16x16x32_bf16(xh[st], bih[0], acci, 0, 0, 0);
          acci = __builtin_amdgcn_mfma_f32_16x16x32_bf16(xl[st], bih[0], acci, 0, 0, 0);
        } else {
          // counted wait: 4 outstanding allowed (= next step's prefetch)
          if (st == CH - 1) asm volatile("s_waitcnt vmcnt(0)" ::: "memory");
          else              asm volatile("s_waitcnt vmcnt(4)" ::: "memory");
          __builtin_amdgcn_sched_barrier(0);  // rule #18
          if (st & 1) {
            acci = __builtin_amdgcn_mfma_f32_16x16x32_bf16(icB0, bih[0], acci, 0, 0, 0);
            acci = __builtin_amdgcn_mfma_f32_16x16x32_bf16(icB1, bih[1], acci, 0, 0, 0);
            acci = __builtin_amdgcn_mfma_f32_16x16x32_bf16(icB2, bih[2], acci, 0, 0, 0);
            acci = __builtin_amdgcn_mfma_f32_16x16x32_bf16(icB3, bih[3], acci, 0, 0, 0);
          } else {
            acci = __builtin_amdgcn_mfma_f32_16x16x32_bf16(icA0, bih[0], acci, 0, 0, 0);
            acci = __builtin_amdgcn_mfma_f32_16x16x32_bf16(icA1, bih[1], acci, 0, 0, 0);
            acci = __builtin_amdgcn_mfma_f32_16x16x32_bf16(icA2, bih[2], acci, 0, 0, 0);
            acci = __builtin_amdgcn_mfma_f32_16x16x32_bf16(icA3, bih[3], acci, 0, 0, 0);
          }
        }

        unsigned short nh[4], nl[4];
#pragma unroll
        for (int r = 0; r < 4; ++r) {
          float v = fast_tanh(acch[r] + accl[r] + acci[r] + bias);
          nh[r] = f2bf(v);
          nl[r] = f2bf(v - bf2f(nh[r]));
        }
        // write h(t) into the other buffer; D layout (m89)
        if (j < NH) {
#pragma unroll
          for (int r = 0; r < 4; ++r) {
            const int m = kg * 4 + r;
            hHi[rb ^ 1][m][j] = nh[r];
            hLo[rb ^ 1][m][j] = nl[r];
          }
        }
      } else {
        // ---- comms wave: store/FC step st-1 (its output is in buf st&1) ----
        if (st >= 1) {
          const int b = st & 1;
          if (l < NL - 1) {
            for (int idx = ln; idx < BPS * (RC / 8); idx += 64) {
              const int rr = idx / 13, c8 = (idx - rr * 13) * 8;
              st16_dev(robc + ((st - 1) * BPS + rr) * RC + c8,
                       *(const short8v*)&hHi[b][rr][c8]);
            }
          } else {
            const int row = ln >> 2, q = ln & 3;
            float sum = 0.f;
#pragma unroll
            for (int e = 0; e < 4; ++e) {
              short8v hv = *(const short8v*)&hHi[b][row][q * 32 + e * 8];
              short8v lv = *(const short8v*)&hLo[b][row][q * 32 + e * 8];
#pragma unroll
              for (int u = 0; u < 8; ++u)
                sum = fmaf(bf2f((unsigned short)hv[u]) + bf2f((unsigned short)lv[u]),
                           fcreg[e * 8 + u], sum);
            }
            sum += __shfl_xor(sum, 1);
            sum += __shfl_xor(sum, 2);
            if (q == 0)
              out[(size_t)(b0 + row) * NT + (c * CH + st - 1)] = sum + fcb;
          }
        }
        // non-blocking readiness probe for chunk c+1
        if (!ready && c + 1 < NTC && ln == 0) {
          const bool okin = (l == 0) || (ld_rlx(pin) >= (unsigned)(c + 2));
          const bool okout = (l == NL - 1) || (c + 1 < D) ||
                             (ld_rlx(pout) >= (unsigned)(c + 2 - D));
          if (okin && okout) { sReadyC = c + 1; ready = true; }
        }
      }

      // blocking fallback for chunk c+1 (rarely taken in steady state)
      if (st == CH - 1 && tid == 0 && c + 1 < NTC) {
        if (sReadyC < c + 1) {
          int ab = 0;
          if (l > 0) ab = wait_ge(pin, (unsigned)(c + 2), abortf);
          if (!ab && l < NL - 1 && c + 1 >= D)
            ab = wait_ge(pout, (unsigned)(c + 2 - D), abortf);
          if (ab) sAbort = 1; else sReadyC = c + 1;
        }
      }
      __syncthreads();
    }

    if (sAbort) return;

    // ---- comms tail (overlaps next chunk's step 0): last plane + publish ----
    if (w == NW) {
      if (l < NL - 1) {
        for (int idx = ln; idx < BPS * (RC / 8); idx += 64) {
          const int rr = idx / 13, c8 = (idx - rr * 13) * 8;
          st16_dev(robc + ((CH - 1) * BPS + rr) * RC + c8,
                   *(const short8v*)&hHi[0][rr][c8]);
        }
      } else {
        const int row = ln >> 2, q = ln & 3;
        float sum = 0.f;
#pragma unroll
        for (int e = 0; e < 4; ++e) {
          short8v hv = *(const short8v*)&hHi[0][row][q * 32 + e * 8];
          short8v lv = *(const short8v*)&hLo[0][row][q * 32 + e * 8];
#pragma unroll
          for (int u = 0; u < 8; ++u)
            sum = fmaf(bf2f((unsigned short)hv[u]) + bf2f((unsigned short)lv[u]),
                       fcreg[e * 8 + u], sum);
        }
        sum += __shfl_xor(sum, 1);
        sum += __shfl_xor(sum, 2);
        if (q == 0)
          out[(size_t)(b0 + row) * NT + (c * CH + CH - 1)] = sum + fcb;
      }
      asm volatile("s_waitcnt vmcnt(0)" ::: "memory");  // stores at L3
      if (ln == 0) st_rlx(pme, (unsigned)(c + 1));
      ready = false;
    }
  }

  // ---- h_final from buffer 0 (last step's output; CH even) ----
  for (int i = tid; i < BPS * NH; i += NTHR) {
    const int r = i / NH, jj = i - r * NH;
    hfin[(size_t)l * NB * NH + (size_t)(b0 + r) * NH + jj] =
        bf2f(hHi[0][r][jj]) + bf2f(hLo[0][r][jj]);
  }
}

extern "C" void kernel_launch(void* const* d_in, const int* in_sizes, int n_in,
                              void* d_out, int out_size, void* d_ws, size_t ws_size,
                              hipStream_t stream) {
  const float* x = (const float*)d_in[0];
  const float* hidden = (const float*)d_in[1];
  const float* w_ih0 = (const float*)d_in[2];
  const float* w_ihL = (const float*)d_in[3];
  const float* w_hh = (const float*)d_in[4];
  const float* b_ih = (const float*)d_in[5];
  const float* b_hh = (const float*)d_in[6];
  const float* fc_w = (const float*)d_in[7];
  const float* fc_b = (const float*)d_in[8];
  float* out = (float*)d_out;
  float* hfin = out + (size_t)NB * NT;
  unsigned* prog = (unsigned*)d_ws;
  unsigned short* ring = (unsigned short*)((char*)d_ws + FLAGBYTES);

  const size_t per_d = (size_t)(NL - 1) * NS * PLANE * 2;  // bytes per depth
  if (ws_size < FLAGBYTES + per_d + 128) return;  // fail safe, no OOB
  int D = 32;
  while (D > 1 && FLAGBYTES + (size_t)D * per_d + 128 > ws_size) D >>= 1;

  zero_flags<<<8, 256, 0, stream>>>(prog);
  rnn_mfma<<<NL * NS, NTHR, 0, stream>>>(x, hidden, w_ih0, w_ihL, w_hh, b_ih,
                                         b_hh, fc_w, fc_b, out, hfin, prog,
                                         ring, D);
}